// Round 11
// baseline (175.962 us; speedup 1.0000x reference)
//
#include <hip/hip_runtime.h>
#include <math.h>

// StatefulRosenberg R18: offload chunk-prefix scan to a tiny 3rd kernel.
//
// R17 post-mortem: f32 wave scan = exactly neutral (174.19 vs 174.09) ->
// the wave scan wasn't the limiting serial segment. Kept (fewer VGPRs).
// Remaining per-block overhead in emit: 8 predicated L2 partial loads +
// 6-step f64 butterfly + rs-LDS reduce, REPLICATED in all 8192 blocks,
// only to compute the chunk prefix. R18 moves that to k_row_scan (16
// blocks, one per row, scans 512 partials -> exclusive pscan; dispatch-
// boundary coherence, no atomics/fences). k_emit's prefix becomes ONE
// wave-uniform f64 load (scalar SMEM path, off the vmcnt chain); its
// pre-barrier critical path is now just f0 -> tsum -> wave scan.
//
// Dead-lane ledger (measured): grid.sync/spin ~0.13us/block (R8,R12);
// per-wave barrier-free prefix (R13/R14); VPT=16 emit (R14: FETCH +25MB);
// 2-chunk live emit at (256,8) (R16: ~10 dword/thread spill); nt wav
// stores (R9: +30MB write amp); f32 wave scan (R17: neutral, kept).
// Kept: oq pre-scan hoist (R9), chain-critical load order (R15), regular
// wav stores, nt oq loads, one f64 wrap + f32 per-element accumulation.

constexpr int BATCH   = 16;
constexpr int T       = 1048576;
constexpr int THREADS = 256;
constexpr int VPT     = 8;                // elements per thread
constexpr int CHUNK   = THREADS * VPT;    // 2048
constexpr int NCHUNK  = T / CHUNK;        // 512

#define INV_SR (1.0f / 48000.0f)

typedef float v4f __attribute__((ext_vector_type(4)));

__device__ __forceinline__ double tree8d(const float* s) {
    return (((double)s[0] + (double)s[1]) + ((double)s[2] + (double)s[3]))
         + (((double)s[4] + (double)s[5]) + ((double)s[6] + (double)s[7]));
}

// ---------------- Pass 1: per-chunk fp64 sums (unchanged) ----------------
__global__ __launch_bounds__(THREADS, 8) void k_chunk_sums(
    const float* __restrict__ f0, double* __restrict__ partial)
{
    const int chunk = blockIdx.x;
    const int row   = blockIdx.y;
    const v4f* base = (const v4f*)(f0 + (size_t)row * T
                     + (size_t)chunk * CHUNK + (size_t)threadIdx.x * VPT);
    v4f v0 = base[0], v1 = base[1];       // regular loads: warm LLC for pass 2
    float st[VPT];
    st[0]=v0.x*INV_SR; st[1]=v0.y*INV_SR; st[2]=v0.z*INV_SR; st[3]=v0.w*INV_SR;
    st[4]=v1.x*INV_SR; st[5]=v1.y*INV_SR; st[6]=v1.z*INV_SR; st[7]=v1.w*INV_SR;
    double s = tree8d(st);
#pragma unroll
    for (int off = 32; off > 0; off >>= 1)
        s += __shfl_down(s, off, 64);
    __shared__ double ws[THREADS / 64];
    const int lane = threadIdx.x & 63, wid = threadIdx.x >> 6;
    if (lane == 0) ws[wid] = s;
    __syncthreads();
    if (threadIdx.x == 0)
        partial[row * NCHUNK + chunk] = ws[0] + ws[1] + ws[2] + ws[3];
}

// ---------------- Pass 1b: exclusive scan of each row's 512 partials -----
__global__ __launch_bounds__(THREADS, 8) void k_row_scan(
    const double* __restrict__ partial, double* __restrict__ pscan)
{
    const int row  = blockIdx.x;
    const int t    = threadIdx.x;
    const int lane = t & 63, wid = t >> 6;
    const double* p = partial + (size_t)row * NCHUNK;
    double v0 = p[2 * t], v1 = p[2 * t + 1];
    double s  = v0 + v1;
    double inc = s;                        // inclusive scan over thread-pairs
#pragma unroll
    for (int off = 1; off < 64; off <<= 1) {
        double n = __shfl_up(inc, off, 64);
        if (lane >= off) inc += n;
    }
    __shared__ double ws[THREADS / 64];
    if (lane == 63) ws[wid] = inc;
    __syncthreads();
    double add = 0.0;
#pragma unroll
    for (int w = 0; w < THREADS / 64; ++w)
        if (w < wid) add += ws[w];
    const double excl = add + (inc - s);   // sum of all pairs before thread t
    double* q = pscan + (size_t)row * NCHUNK;
    q[2 * t]     = excl;                   // prefix of chunk 2t
    q[2 * t + 1] = excl + v0;              // prefix of chunk 2t+1
}

// ---------------- Pass 2: scalar prefix + wave scan + Rosenberg pulse ----
__global__ __launch_bounds__(THREADS, 8) void k_emit(
    const float* __restrict__ f0, const float* __restrict__ oq,
    const double* __restrict__ pscan, const float* __restrict__ phase_state,
    float* __restrict__ wav, float* __restrict__ next_state)
{
    const int chunk = blockIdx.x;
    const int row   = blockIdx.y;
    const int lane  = threadIdx.x & 63, wid = threadIdx.x >> 6;
    const size_t base_idx = (size_t)row * T + (size_t)chunk * CHUNK
                          + (size_t)threadIdx.x * VPT;

    __shared__ double ws[THREADS / 64];   // wave totals (f64)

    // ---- chunk prefix: ONE wave-uniform f64 load (scalar path, lgkmcnt,
    //      independent of the vmcnt chain) ----
    const double chunkpref = pscan[(size_t)row * NCHUNK + chunk];
    const float  pstate    = phase_state[row];

    // ---- vector loads in CHAIN-CRITICAL order (vmcnt ordered):
    // (1) f0 -- first consumer (tsum/scan); LLC-hot from pass 1
    const v4f* fb = (const v4f*)(f0 + base_idx);
    v4f f_0 = fb[0], f_1 = fb[1];
    // (2) oq -- consumed LAST (pulse loop); HBM latency hides under scan
    const v4f* ob = (const v4f*)(oq + base_idx);
    v4f o_0 = __builtin_nontemporal_load(ob + 0);
    v4f o_1 = __builtin_nontemporal_load(ob + 1);

    // ---- f32 steps + thread sums (f32 for scan, f64 for totals) ----
    float st[VPT];
    st[0]=f_0.x*INV_SR; st[1]=f_0.y*INV_SR; st[2]=f_0.z*INV_SR; st[3]=f_0.w*INV_SR;
    st[4]=f_1.x*INV_SR; st[5]=f_1.y*INV_SR; st[6]=f_1.z*INV_SR; st[7]=f_1.w*INV_SR;
    float ts32 = (((st[0]+st[1])+(st[2]+st[3])) + ((st[4]+st[5])+(st[6]+st[7])));
    double tsum = tree8d(st);             // f64 total feeds cross-wave path

    // ---- intra-wave inclusive scan in f32 (err ~4e-8 << 3.9e-3 tol) ----
    float inc = ts32;
#pragma unroll
    for (int off = 1; off < 64; off <<= 1) {
        float n = __shfl_up(inc, off, 64);
        if (lane >= off) inc += n;
    }
    // wave total in f64 (exact per-thread f64 sums, reduced once per wave)
    double wtot = tsum;
#pragma unroll
    for (int off = 32; off > 0; off >>= 1)
        wtot += __shfl_down(wtot, off, 64);
    if (lane == 0) ws[wid] = wtot;
    __syncthreads();

    double run = (double)pstate + chunkpref + (double)(inc - ts32);
#pragma unroll
    for (int w = 0; w < THREADS / 64; ++w)
        if (w < wid) run += ws[w];

    // next_state: unwrapped final phase, written by the last chunk's thread 0
    if (chunk == NCHUNK - 1 && threadIdx.x == 0)
        next_state[row] = (float)((double)pstate + chunkpref
                                  + ws[0] + ws[1] + ws[2] + ws[3]);

    // wrap the thread base ONCE in f64; per-element accumulation is f32.
    // max unwrapped value < 1 + 8*(1/48000) -> single fract suffices.
    float runf = (float)(run - floor(run));

    float o[VPT];
    o[0]=o_0.x; o[1]=o_0.y; o[2]=o_0.z; o[3]=o_0.w;
    o[4]=o_1.x; o[5]=o_1.y; o[6]=o_1.z; o[7]=o_1.w;

    // ---- accumulate + pulse; one v_cos per element, arg in revolutions ----
    float outv[VPT];
#pragma unroll
    for (int i = 0; i < VPT; ++i) {
        runf += st[i];
        float ph  = __builtin_amdgcn_fractf(runf);   // wrapped phase in [0,1)
        float oqv = o[i];
        float tp  = oqv * 0.66f;
        bool  is_rise  = ph < tp;
        bool  in_pulse = ph < oqv;
        float num = is_rise ? ph : (ph - tp);
        float den = is_rise ? fmaf(oqv, 0.66f, 1e-6f)    // tp + eps
                            : fmaf(oqv, 0.68f, 1e-6f);   // 2*tn + eps
        // cos(pi * num/den) == v_cos(0.5 * num/den revolutions)
        float rev = 0.5f * num * __builtin_amdgcn_rcpf(den);
        float c2  = __builtin_amdgcn_cosf(rev);
        outv[i] = is_rise ? 0.5f * (1.0f - c2) : (in_pulse ? c2 : 0.0f);
    }

    v4f* wb = (v4f*)(wav + base_idx);
#pragma unroll
    for (int j = 0; j < VPT / 4; ++j) {
        v4f vv;
        vv.x = outv[4 * j + 0]; vv.y = outv[4 * j + 1];
        vv.z = outv[4 * j + 2]; vv.w = outv[4 * j + 3];
        wb[j] = vv;   // regular store: L2 merges partial lines (R9 lesson)
    }
}

extern "C" void kernel_launch(void* const* d_in, const int* in_sizes, int n_in,
                              void* d_out, int out_size, void* d_ws, size_t ws_size,
                              hipStream_t stream)
{
    const float* f0          = (const float*)d_in[0];
    const float* oq          = (const float*)d_in[1];
    const float* phase_state = (const float*)d_in[2];
    float* out = (float*)d_out;                 // [B*T] wav, then [B] next_state

    double* partial = (double*)d_ws;                          // 64 KB
    double* pscan   = partial + (size_t)BATCH * NCHUNK;       // 64 KB

    dim3 grid(NCHUNK, BATCH);
    k_chunk_sums<<<grid, THREADS, 0, stream>>>(f0, partial);
    k_row_scan<<<BATCH, THREADS, 0, stream>>>(partial, pscan);
    k_emit<<<grid, THREADS, 0, stream>>>(f0, oq, pscan, phase_state,
                                         out, out + (size_t)BATCH * T);
}

// Round 12
// 171.552 us; speedup vs baseline: 1.0257x; 1.0257x over previous
//
#include <hip/hip_runtime.h>
#include <math.h>

// StatefulRosenberg R19: split-half layout -> perfectly coalesced accesses.
//
// R18 post-mortem: prefix-offload neutral (176.0) -> prefix machinery is
// not the limiter. Third round at 174-176. Reverted to 2-kernel R15/R17.
//
// R19 theory: thread t owning [8t,8t+8) makes EVERY vector mem instruction
// stride-32B (two v4f at 32t, 32t+16): one instr touches 16 cache lines
// HALF each -> 16 partial-line requests vs 8 full-line. 2x transaction
// count through TA/L1/L2 for the same bytes. Consistent with: emit pinned
// at 3.8 TB/s (58% of fills' 6.6), VALU 23%, occ 55%, nothing saturated,
// all structural fixes flat. Fix: split each 2048-chunk into halves;
// thread t owns [4t,4t+4) of half A and [1024+4t,+4) of half B -> every
// load/store is unit-stride 16B/lane (full lines). Same 8 elem/thread
// (no register cost). Scan: two interleaved f32 wave scans (A,B) --
// B prefix = totalA (free from lane-63 wave totals in LDS, f32: in-chunk
// sums <=0.043, err ~1e-9) + B scan. f64 butterfly chunk prefix kept
// (values ~10.9). Same layout fix in pass 1.
//
// Dead-lane ledger (measured): grid.sync/spin ~0.13us/block (R8,R12);
// per-wave barrier-free prefix (R13/R14); VPT=16 (R14: FETCH +25MB);
// 2-chunk live state (R16: spill); nt wav stores (R9: +30MB write amp);
// f32 wave scan (R17: neutral, kept); prefix-offload 3rd kernel (R18:
// neutral-negative). Kept: oq pre-scan hoist (R9), chain-critical load
// order f0->partials->oq (R15), regular wav stores, nt oq loads, one
// f64 wrap + f32 per-element accumulation.

constexpr int BATCH   = 16;
constexpr int T       = 1048576;
constexpr int THREADS = 256;
constexpr int VPT     = 8;                // elements per thread (4 + 4)
constexpr int CHUNK   = THREADS * VPT;    // 2048
constexpr int HALF    = CHUNK / 2;        // 1024
constexpr int NCHUNK  = T / CHUNK;        // 512

#define INV_SR (1.0f / 48000.0f)

typedef float v4f __attribute__((ext_vector_type(4)));

// ---------------- Pass 1: per-chunk fp64 sums (coalesced layout) ---------
__global__ __launch_bounds__(THREADS, 8) void k_chunk_sums(
    const float* __restrict__ f0, double* __restrict__ partial)
{
    const int chunk = blockIdx.x;
    const int row   = blockIdx.y;
    const size_t cb = (size_t)row * T + (size_t)chunk * CHUNK;
    // unit-stride 16B/lane: each instruction covers full cache lines
    v4f v0 = *(const v4f*)(f0 + cb + 4 * threadIdx.x);          // half A
    v4f v1 = *(const v4f*)(f0 + cb + HALF + 4 * threadIdx.x);   // half B
    double s = (((double)(v0.x*INV_SR) + (double)(v0.y*INV_SR))
             +  ((double)(v0.z*INV_SR) + (double)(v0.w*INV_SR)))
             + (((double)(v1.x*INV_SR) + (double)(v1.y*INV_SR))
             +  ((double)(v1.z*INV_SR) + (double)(v1.w*INV_SR)));
#pragma unroll
    for (int off = 32; off > 0; off >>= 1)
        s += __shfl_down(s, off, 64);
    __shared__ double ws[THREADS / 64];
    const int lane = threadIdx.x & 63, wid = threadIdx.x >> 6;
    if (lane == 0) ws[wid] = s;
    __syncthreads();
    if (threadIdx.x == 0)
        partial[row * NCHUNK + chunk] = ws[0] + ws[1] + ws[2] + ws[3];
}

// ---------------- Pass 2: prefix + dual half-scan + Rosenberg pulse ------
__global__ __launch_bounds__(THREADS, 8) void k_emit(
    const float* __restrict__ f0, const float* __restrict__ oq,
    const double* __restrict__ partial, const float* __restrict__ phase_state,
    float* __restrict__ wav, float* __restrict__ next_state)
{
    const int chunk = blockIdx.x;
    const int row   = blockIdx.y;
    const int lane  = threadIdx.x & 63, wid = threadIdx.x >> 6;
    const size_t cb = (size_t)row * T + (size_t)chunk * CHUNK;
    const size_t tA = cb + 4 * threadIdx.x;          // half-A slot (16B/lane)
    const size_t tB = tA + HALF;                     // half-B slot

    __shared__ double rs[THREADS / 64];   // chunk-prefix partial reduce (f64)
    __shared__ float  wsA[THREADS / 64];  // half-A wave totals (f32)
    __shared__ float  wsB[THREADS / 64];  // half-B wave totals (f32)

    // ---- loads in CHAIN-CRITICAL order (vmcnt ordered, oldest first):
    // (1) f0 halves -- first consumers (step sums / scans); LLC-hot
    v4f fA = *(const v4f*)(f0 + tA);
    v4f fB = *(const v4f*)(f0 + tB);
    // (2) chunk-prefix partials -- butterfly; L2-hot
    double pv = 0.0;
    if ((int)threadIdx.x < chunk)       pv  = partial[row * NCHUNK + threadIdx.x];
    if ((int)threadIdx.x + 256 < chunk) pv += partial[row * NCHUNK + threadIdx.x + 256];
    const float pstate = phase_state[row];
    // (3) oq -- consumed LAST (pulse loops); HBM latency hides under scans
    v4f oA = __builtin_nontemporal_load((const v4f*)(oq + tA));
    v4f oB = __builtin_nontemporal_load((const v4f*)(oq + tB));

    // ---- f32 steps + span sums ----
    float sa[4] = {fA.x*INV_SR, fA.y*INV_SR, fA.z*INV_SR, fA.w*INV_SR};
    float sb[4] = {fB.x*INV_SR, fB.y*INV_SR, fB.z*INV_SR, fB.w*INV_SR};
    float tsA = (sa[0] + sa[1]) + (sa[2] + sa[3]);
    float tsB = (sb[0] + sb[1]) + (sb[2] + sb[3]);

    // ---- chunk prefix butterfly (f64, values ~10.9) ----
#pragma unroll
    for (int off = 32; off > 0; off >>= 1)
        pv += __shfl_down(pv, off, 64);
    if (lane == 0) rs[wid] = pv;

    // ---- two interleaved f32 wave scans (independent chains, 2x ILP) ----
    float incA = tsA, incB = tsB;
#pragma unroll
    for (int off = 1; off < 64; off <<= 1) {
        float nA = __shfl_up(incA, off, 64);
        float nB = __shfl_up(incB, off, 64);
        if (lane >= off) { incA += nA; incB += nB; }
    }
    if (lane == 63) { wsA[wid] = incA; wsB[wid] = incB; }   // wave totals free
    __syncthreads();

    const double chunkpref = rs[0] + rs[1] + rs[2] + rs[3];
    float crossA = 0.0f, crossB = 0.0f;
#pragma unroll
    for (int w = 0; w < THREADS / 64; ++w)
        if (w < wid) { crossA += wsA[w]; crossB += wsB[w]; }
    const float totalA = (wsA[0] + wsA[1]) + (wsA[2] + wsA[3]);

    const double dbase = (double)pstate + chunkpref;
    double runA = dbase + (double)(crossA + (incA - tsA));
    double runB = dbase + (double)(totalA + crossB + (incB - tsB));

    // next_state: unwrapped final phase (last chunk, thread 0)
    if (chunk == NCHUNK - 1 && threadIdx.x == 0) {
        const float totalB = (wsB[0] + wsB[1]) + (wsB[2] + wsB[3]);
        next_state[row] = (float)(dbase + (double)(totalA + totalB));
    }

    // wrap each thread base ONCE in f64; f32 per-element accumulation
    // (max unwrapped < 1 + 4/48000 -> single fract suffices)
    float runfA = (float)(runA - floor(runA));
    float runfB = (float)(runB - floor(runB));

    float oAa[4] = {oA.x, oA.y, oA.z, oA.w};
    float oBa[4] = {oB.x, oB.y, oB.z, oB.w};
    float outA[4], outB[4];
#pragma unroll
    for (int i = 0; i < 4; ++i) {
        // two independent chains -> ILP in the transcendental pipe
        runfA += sa[i];
        runfB += sb[i];
        float phA = __builtin_amdgcn_fractf(runfA);
        float phB = __builtin_amdgcn_fractf(runfB);
        float qA = oAa[i], qB = oBa[i];
        float tpA = qA * 0.66f, tpB = qB * 0.66f;
        bool  rA = phA < tpA,  rB = phB < tpB;
        bool  pA = phA < qA,   pB = phB < qB;
        float numA = rA ? phA : (phA - tpA);
        float numB = rB ? phB : (phB - tpB);
        float denA = rA ? fmaf(qA, 0.66f, 1e-6f) : fmaf(qA, 0.68f, 1e-6f);
        float denB = rB ? fmaf(qB, 0.66f, 1e-6f) : fmaf(qB, 0.68f, 1e-6f);
        float revA = 0.5f * numA * __builtin_amdgcn_rcpf(denA);
        float revB = 0.5f * numB * __builtin_amdgcn_rcpf(denB);
        float cA = __builtin_amdgcn_cosf(revA);
        float cB = __builtin_amdgcn_cosf(revB);
        outA[i] = rA ? 0.5f * (1.0f - cA) : (pA ? cA : 0.0f);
        outB[i] = rB ? 0.5f * (1.0f - cB) : (pB ? cB : 0.0f);
    }

    // unit-stride coalesced stores (full cache lines per instruction)
    v4f vA; vA.x=outA[0]; vA.y=outA[1]; vA.z=outA[2]; vA.w=outA[3];
    v4f vB; vB.x=outB[0]; vB.y=outB[1]; vB.z=outB[2]; vB.w=outB[3];
    *(v4f*)(wav + tA) = vA;   // regular stores (R9 lesson)
    *(v4f*)(wav + tB) = vB;
}

extern "C" void kernel_launch(void* const* d_in, const int* in_sizes, int n_in,
                              void* d_out, int out_size, void* d_ws, size_t ws_size,
                              hipStream_t stream)
{
    const float* f0          = (const float*)d_in[0];
    const float* oq          = (const float*)d_in[1];
    const float* phase_state = (const float*)d_in[2];
    float* out = (float*)d_out;                 // [B*T] wav, then [B] next_state

    double* partial = (double*)d_ws;            // B*NCHUNK doubles (64 KB)

    dim3 grid(NCHUNK, BATCH);
    k_chunk_sums<<<grid, THREADS, 0, stream>>>(f0, partial);
    k_emit<<<grid, THREADS, 0, stream>>>(f0, oq, partial, phase_state,
                                         out, out + (size_t)BATCH * T);
}